// Round 2
// baseline (481.160 us; speedup 1.0000x reference)
//
#include <hip/hip_runtime.h>
#include <math.h>

// ---- problem constants ----
#define NBASIS 8        // G+K = 5+3
#define NKNOT  12       // G+2K+1
#define D0 12
#define D1 64
#define D2 64
#define D3 24
#define HWP 4096        // 64*64 pixels per image
#define NROWS (32 * HWP)
#define BLOCK 128

// Packed weight sizes (floats): W[(i*9+g)*out + o]; g<8 -> coef*ss, g==8 -> sb
#define NW0 (D0 * 9 * D1)              // 6912
#define NW1 (D1 * 9 * D2)              // 36864
#define NW2 (D2 * 9 * D3)              // 13824
#define NWTOT (NW0 + NW1 + NW2)        // 57600
#define WBYTES (NWTOT * sizeof(float)) // 230400

// Fallback storage if ws_size is too small (same codegen path: passed as arg).
__device__ __align__(16) float g_Wfallback[NWTOT];

__device__ __forceinline__ float packw(const float* __restrict__ coef,
                                       const float* __restrict__ sb,
                                       const float* __restrict__ ss,
                                       int out_dim, int idx) {
    int o = idx % out_dim;
    int k = idx / out_dim;
    int i = k / 9, g = k % 9;
    return (g < 8) ? coef[(i * out_dim + o) * NBASIS + g] * ss[i * out_dim + o]
                   : sb[i * out_dim + o];
}

__global__ void pack_all(float* __restrict__ W,
                         const float* __restrict__ c0, const float* __restrict__ b0, const float* __restrict__ s0,
                         const float* __restrict__ c1, const float* __restrict__ b1, const float* __restrict__ s1,
                         const float* __restrict__ c2, const float* __restrict__ b2, const float* __restrict__ s2) {
    int idx = blockIdx.x * blockDim.x + threadIdx.x;
    if (idx < NW0) {
        W[idx] = packw(c0, b0, s0, D1, idx);
    } else if (idx < NW0 + NW1) {
        int j = idx - NW0;
        W[NW0 + j] = packw(c1, b1, s1, D2, j);
    } else if (idx < NWTOT) {
        int j = idx - (NW0 + NW1);
        W[NW0 + NW1 + j] = packw(c2, b2, s2, D3, j);
    }
}

// Inner GEMM step over one input feature's 9 augmented values (a[0..7]=basis, a[8]=silu).
// Weight addresses are wave-uniform + the pointer is readonly/noalias -> s_load,
// so each FMA reads its weight directly from an SGPR.
#define KAN_INNER(OUTDIM, WBASE, ACC)                                          \
    {                                                                          \
        const float4* Wr = reinterpret_cast<const float4*>(WBASE);             \
        _Pragma("unroll") for (int g = 0; g < 9; ++g) {                        \
            _Pragma("unroll") for (int q = 0; q < (OUTDIM) / 4; ++q) {         \
                float4 w = Wr[g * ((OUTDIM) / 4) + q];                         \
                ACC[4 * q + 0] = fmaf(a[g], w.x, ACC[4 * q + 0]);              \
                ACC[4 * q + 1] = fmaf(a[g], w.y, ACC[4 * q + 1]);              \
                ACC[4 * q + 2] = fmaf(a[g], w.z, ACC[4 * q + 2]);              \
                ACC[4 * q + 3] = fmaf(a[g], w.w, ACC[4 * q + 3]);              \
            }                                                                  \
        }                                                                      \
    }

__device__ __forceinline__ float sgpr(float x) {
    return __uint_as_float(__builtin_amdgcn_readfirstlane(__float_as_uint(x)));
}

__global__ __launch_bounds__(BLOCK, 2) void kan_main(const float* __restrict__ X,
                                                     float* __restrict__ Yout,
                                                     const float* __restrict__ grid,
                                                     const float* __restrict__ W0,
                                                     const float* __restrict__ W1,
                                                     const float* __restrict__ W2) {
    // feature-major: hbuf[feature][lane-in-block]; each thread touches only its
    // own column -> conflict-free AND barrier-free.
    __shared__ float hbuf[D1 * BLOCK];   // 32 KiB -> 5 blocks/CU

    const int tid = threadIdx.x;
    const int row = blockIdx.x * BLOCK + tid;
    const int b = row >> 12;     // / 4096
    const int p = row & 4095;

    // Uniform knots + per-level knot-span reciprocals, pinned to SGPRs.
    float gk[NKNOT];
#pragma unroll
    for (int j = 0; j < NKNOT; ++j) gk[j] = sgpr(grid[j]);   // all grid rows identical
    float r1[11], r2[10], r3[9];
#pragma unroll
    for (int j = 0; j < 11; ++j) r1[j] = sgpr(1.0f / (gk[j + 1] - gk[j]));
#pragma unroll
    for (int j = 0; j < 10; ++j) r2[j] = sgpr(1.0f / (gk[j + 2] - gk[j]));
#pragma unroll
    for (int j = 0; j < 9; ++j)  r3[j] = sgpr(1.0f / (gk[j + 3] - gk[j]));

    // Cox-de Boor K=3, hat-function level 1 (exactly matches the reference's
    // degree-0 truncation incl. out-of-range-x -> all-zero), shared d[j]=v-gk[j].
    auto feats = [&](float v, float* a) {
        float d[NKNOT];
#pragma unroll
        for (int j = 0; j < NKNOT; ++j) d[j] = v - gk[j];
        float B[10];
#pragma unroll
        for (int j = 0; j < 10; ++j) {
            float m1 = d[j] * r1[j];
            float m2 = -d[j + 2] * r1[j + 1];
            B[j] = fmaxf(0.0f, fminf(m1, m2));   // hat_j(v)
        }
#pragma unroll
        for (int j = 0; j < 9; ++j) {
            float q = d[j + 3] * r2[j + 1];
            B[j] = fmaf(-q, B[j + 1], d[j] * r2[j] * B[j]);
        }
#pragma unroll
        for (int j = 0; j < 8; ++j) {
            float q = d[j + 4] * r3[j + 1];
            a[j] = fmaf(-q, B[j + 1], d[j] * r3[j] * B[j]);
        }
        a[8] = v / (1.0f + __expf(-v));          // silu
    };

    float acc[D1];

    // ---- layer 0: 12 -> 64 (input from global, NCHW), next-feature prefetch ----
#pragma unroll
    for (int o = 0; o < D1; ++o) acc[o] = 0.0f;
    float vnext = X[(b * D0 + 0) * HWP + p];
#pragma unroll 1
    for (int i = 0; i < D0; ++i) {
        float v = vnext;
        if (i + 1 < D0) vnext = X[(b * D0 + i + 1) * HWP + p];
        float a[9];
        feats(v, a);
        KAN_INNER(D1, W0 + i * 9 * D1, acc)
    }
#pragma unroll
    for (int o = 0; o < D1; ++o) hbuf[o * BLOCK + tid] = acc[o];

    // ---- layer 1: 64 -> 64 ----
#pragma unroll
    for (int o = 0; o < D1; ++o) acc[o] = 0.0f;
    vnext = hbuf[0 * BLOCK + tid];
#pragma unroll 1
    for (int i = 0; i < D1; ++i) {
        float v = vnext;
        if (i + 1 < D1) vnext = hbuf[(i + 1) * BLOCK + tid];
        float a[9];
        feats(v, a);
        KAN_INNER(D2, W1 + i * 9 * D2, acc)
    }
#pragma unroll
    for (int o = 0; o < D2; ++o) hbuf[o * BLOCK + tid] = acc[o];

    // ---- layer 2: 64 -> 24 ----
    float acc3[D3];
#pragma unroll
    for (int o = 0; o < D3; ++o) acc3[o] = 0.0f;
    vnext = hbuf[0 * BLOCK + tid];
#pragma unroll 1
    for (int i = 0; i < D2; ++i) {
        float v = vnext;
        if (i + 1 < D2) vnext = hbuf[(i + 1) * BLOCK + tid];
        float a[9];
        feats(v, a);
        KAN_INNER(D3, W2 + i * 9 * D3, acc3)
    }

    // ---- output: (32, 24, 64, 64) ----
#pragma unroll
    for (int o = 0; o < D3; ++o)
        Yout[(b * D3 + o) * HWP + p] = acc3[o];
}

extern "C" void kernel_launch(void* const* d_in, const int* in_sizes, int n_in,
                              void* d_out, int out_size, void* d_ws, size_t ws_size,
                              hipStream_t stream) {
    const float* X     = (const float*)d_in[0];
    const float* grid0 = (const float*)d_in[1];
    const float* coef0 = (const float*)d_in[2];
    const float* sb0   = (const float*)d_in[3];
    const float* ss0   = (const float*)d_in[4];
    const float* coef1 = (const float*)d_in[6];
    const float* sb1   = (const float*)d_in[7];
    const float* ss1   = (const float*)d_in[8];
    const float* coef2 = (const float*)d_in[10];
    const float* sb2   = (const float*)d_in[11];
    const float* ss2   = (const float*)d_in[12];
    float* Yout = (float*)d_out;

    // Weight buffer: prefer d_ws; fall back to a device global (same codegen,
    // both reach the kernel as a readonly noalias arg).
    float* W = (float*)d_ws;
    if (ws_size < WBYTES) {
        void* sym = nullptr;
        hipGetSymbolAddress(&sym, HIP_SYMBOL(g_Wfallback));
        W = (float*)sym;
    }

    // 57600 weights / 256 = 225 blocks
    hipLaunchKernelGGL(pack_all, dim3((NWTOT + 255) / 256), dim3(256), 0, stream, W,
                       coef0, sb0, ss0, coef1, sb1, ss1, coef2, sb2, ss2);
    // 131072 rows / 128 = 1024 blocks; 32KB LDS -> 5 blocks/CU
    hipLaunchKernelGGL(kan_main, dim3(NROWS / BLOCK), dim3(BLOCK), 0, stream,
                       X, Yout, grid0, W, W + NW0, W + NW0 + NW1);
}

// Round 4
// 241.617 us; speedup vs baseline: 1.9914x; 1.9914x over previous
//
#include <hip/hip_runtime.h>
#include <math.h>

// ---- problem constants ----
#define D0 12
#define D1 64
#define D2 64
#define D3 24
#define HWP 4096
#define NROWS (32 * HWP)

#define ROWS 32            // rows per block
#define BLK 256            // threads (4 waves)

// K dims (k = 9*i + g), padded to multiple of 32
#define K0 128             // real 108
#define K1 576
#define K2 576
#define S0c (K0/32)        // 4 k-steps
#define S1c (K1/32)        // 18
#define S2c (K2/32)        // 18
#define T0c 4              // col tiles of 16 (64 cols)
#define T1c 4
#define T2c 2              // 32 cols (24 real)

// packed-W element counts (ushort) per panel, fragment-linear layout
#define WE0 (S0c*T0c*64*8) //  8192
#define WE1 (S1c*T1c*64*8) // 36864
#define WE2 (S2c*T2c*64*8) // 18432
#define WE_ALL (WE0+WE1+WE2)          // 63488 per panel (hi, lo)
#define WBYTES (2*WE_ALL*sizeof(unsigned short))  // 253952 B

typedef __attribute__((ext_vector_type(8))) short short8;
typedef __attribute__((ext_vector_type(4))) float float4v;

__device__ __align__(16) unsigned short g_Wfb[2 * WE_ALL];  // fallback if ws too small

__device__ __forceinline__ unsigned short f2bf(float f) {
    unsigned int b = __float_as_uint(f);
    unsigned int r = (b + 0x7FFFu + ((b >> 16) & 1u)) >> 16;   // RNE
    return (unsigned short)r;
}
__device__ __forceinline__ float bf2f(unsigned short u) {
    return __uint_as_float(((unsigned int)u) << 16);
}

// ---- pack kernel: W[(9i+g)][o] -> bf16 hi/lo in MFMA-B fragment-linear layout ----
// elem index within a layer: ((s*T + t)*64 + lane)*8 + j ; k = 32s + 8*(lane>>4) + j ; o = 16t + (lane&15)
__global__ void pack_w(unsigned short* __restrict__ Wpk,
                       const float* __restrict__ c0, const float* __restrict__ b0, const float* __restrict__ s0_,
                       const float* __restrict__ c1, const float* __restrict__ b1, const float* __restrict__ s1_,
                       const float* __restrict__ c2, const float* __restrict__ b2, const float* __restrict__ s2_) {
    int idx = blockIdx.x * 256 + threadIdx.x;
    if (idx >= WE_ALL) return;
    int base, T, in, out;
    const float *cf, *sb, *ss;
    if (idx < WE0)            { base = idx;             T = T0c; in = D0; out = D1; cf = c0; sb = b0; ss = s0_; }
    else if (idx < WE0 + WE1) { base = idx - WE0;       T = T1c; in = D1; out = D2; cf = c1; sb = b1; ss = s1_; }
    else                      { base = idx - WE0 - WE1; T = T2c; in = D2; out = D3; cf = c2; sb = b2; ss = s2_; }
    int j  = base & 7;
    int l  = (base >> 3) & 63;
    int st = base >> 9;
    int t  = st % T;
    int s  = st / T;
    int k  = 32 * s + 8 * (l >> 4) + j;
    int o  = 16 * t + (l & 15);
    float w = 0.0f;
    int i = k / 9, g = k % 9;
    if (i < in && o < out)
        w = (g < 8) ? cf[(i * out + o) * 8 + g] * ss[i * out + o] : sb[i * out + o];
    unsigned short hi = f2bf(w);
    unsigned short lo = f2bf(w - bf2f(hi));
    Wpk[idx] = hi;
    Wpk[idx + WE_ALL] = lo;
}

// ---- main fused kernel ----
__device__ __forceinline__ float sgpr(float x) {
    return __uint_as_float(__builtin_amdgcn_readfirstlane(__float_as_uint(x)));
}

#define MFMA16(a, b, c) __builtin_amdgcn_mfma_f32_16x16x32_bf16((a), (b), (c), 0, 0, 0)

// A-fragment read from swizzled LDS panel: row R = 16m + r15, k0 = 32s + 16*kg bytes
#define LDA(m, s) (*(const short8*)(pb + ((((16*(m) + r15) * 1152) + 64*(s) + 16*kg) ^ swA)))

// depth-2 W prefetch (VGPR pressure: keep only 2 hi/lo pairs live)
template <int NS, int T>
__device__ __forceinline__ void mfma_layer(const unsigned short* __restrict__ WH,
                                           const unsigned short* __restrict__ WL,
                                           int w, int lane, int r15, int kg, int swA,
                                           const char* pb, float4v& acc0, float4v& acc1) {
    short8 wh[NS], wl[NS];
#pragma unroll
    for (int s = 0; s < (NS < 2 ? NS : 2); ++s) {
        wh[s] = *(const short8*)(WH + (((size_t)(s * T + w) * 64 + lane) * 8));
        wl[s] = *(const short8*)(WL + (((size_t)(s * T + w) * 64 + lane) * 8));
    }
#pragma unroll
    for (int s = 0; s < NS; ++s) {
        if (s + 2 < NS) {
            wh[s + 2] = *(const short8*)(WH + (((size_t)((s + 2) * T + w) * 64 + lane) * 8));
            wl[s + 2] = *(const short8*)(WL + (((size_t)((s + 2) * T + w) * 64 + lane) * 8));
        }
        short8 a0 = LDA(0, s);
        short8 a1 = LDA(1, s);
        acc0 = MFMA16(a0, wh[s], acc0);
        acc0 = MFMA16(a0, wl[s], acc0);
        acc1 = MFMA16(a1, wh[s], acc1);
        acc1 = MFMA16(a1, wl[s], acc1);
    }
}

__global__ __launch_bounds__(BLK, 4) void kan_mfma(const float* __restrict__ X,
                                                   float* __restrict__ Y,
                                                   const float* __restrict__ grid,
                                                   const unsigned short* __restrict__ Wpk) {
    __shared__ __align__(16) unsigned short panel[ROWS * 576];   // 36864 B
    char* pb = (char*)&panel[0];

    const int tid  = threadIdx.x;
    const int lane = tid & 63;
    const int w    = tid >> 6;        // wave id = coltile
    const int r15  = lane & 15;
    const int kg   = lane >> 4;       // 0..3
    const int swA  = (r15 & 7) << 4;  // read-side XOR swizzle (R&7 == r15&7 for R=16m+r15)

    const int b  = blockIdx.x >> 7;          // image
    const int p0 = (blockIdx.x & 127) * 32;  // pixel base for this block's 32 rows

    // knots + knot-span reciprocals, pinned to SGPRs (all grid rows identical)
    float gk[12];
#pragma unroll
    for (int j = 0; j < 12; ++j) gk[j] = sgpr(grid[j]);
    float r1[11], r2[10], r3[9];
#pragma unroll
    for (int j = 0; j < 11; ++j) r1[j] = sgpr(1.0f / (gk[j + 1] - gk[j]));
#pragma unroll
    for (int j = 0; j < 10; ++j) r2[j] = sgpr(1.0f / (gk[j + 2] - gk[j]));
#pragma unroll
    for (int j = 0; j < 9; ++j)  r3[j] = sgpr(1.0f / (gk[j + 3] - gk[j]));

    // Cox-de Boor K=3 via hat functions (fp32-validated in round 2) + silu
    auto feats = [&](float v, float* a) {
        float d[12];
#pragma unroll
        for (int j = 0; j < 12; ++j) d[j] = v - gk[j];
        float B[10];
#pragma unroll
        for (int j = 0; j < 10; ++j) {
            float m1 = d[j] * r1[j];
            float m2 = -d[j + 2] * r1[j + 1];
            B[j] = fmaxf(0.0f, fminf(m1, m2));
        }
#pragma unroll
        for (int j = 0; j < 9; ++j) {
            float q = d[j + 3] * r2[j + 1];
            B[j] = fmaf(-q, B[j + 1], d[j] * r2[j] * B[j]);
        }
#pragma unroll
        for (int j = 0; j < 8; ++j) {
            float q = d[j + 4] * r3[j + 1];
            a[j] = fmaf(-q, B[j + 1], d[j] * r3[j] * B[j]);
        }
        a[8] = v / (1.0f + __expf(-v));
    };

    // write one eval's 9 entries (k = 9c+g) to the swizzled panel
    auto write9 = [&](int R, int c, const float* a) {
        int sw = (R & 7) << 4;
        int rb = R * 1152 + 18 * c;
#pragma unroll
        for (int g = 0; g < 9; ++g)
            *(unsigned short*)(pb + ((rb + 2 * g) ^ sw)) = f2bf(a[g]);
    };

    const unsigned short* WH0 = Wpk;
    const unsigned short* WH1 = Wpk + WE0;
    const unsigned short* WH2 = Wpk + WE0 + WE1;
    const unsigned short* WL0 = Wpk + WE_ALL;
    const unsigned short* WL1 = Wpk + WE_ALL + WE0;
    const unsigned short* WL2 = Wpk + WE_ALL + WE0 + WE1;

    // ---- phase 0: build layer-0 A-panel from X (32 rows x 12 feats = 384 evals) ----
    for (int idx = tid; idx < 640; idx += BLK) {      // zero pad k in [108,128)
        int R = idx / 20, kk = 108 + idx % 20;
        *(unsigned short*)(pb + ((R * 1152 + 2 * kk) ^ ((R & 7) << 4))) = 0;
    }
    {
        int R = tid & 31, i = tid >> 5;
        float v = X[(b * D0 + i) * HWP + p0 + R];
        float a[9]; feats(v, a);
        write9(R, i, a);
        if (tid < 128) {
            int R2 = (tid + 256) & 31, i2 = (tid + 256) >> 5;
            float v2 = X[(b * D0 + i2) * HWP + p0 + R2];
            float a2[9]; feats(v2, a2);
            write9(R2, i2, a2);
        }
    }
    __syncthreads();

    // ---- layer 0 MFMA: K=128, 4 coltiles ----
    float4v acc0 = {0.f, 0.f, 0.f, 0.f}, acc1 = {0.f, 0.f, 0.f, 0.f};
    mfma_layer<S0c, T0c>(WH0, WL0, w, lane, r15, kg, swA, pb, acc0, acc1);
    __syncthreads();

    // ---- layer-1 A-panel from acc (each lane: 2 tiles x 4 regs = 8 evals) ----
#pragma unroll
    for (int m = 0; m < 2; ++m)
#pragma unroll
        for (int reg = 0; reg < 4; ++reg) {
            int R = 16 * m + 4 * kg + reg;            // C/D row mapping (m89)
            int c = 16 * w + r15;                     // C/D col mapping
            float a[9]; feats(m == 0 ? acc0[reg] : acc1[reg], a);
            write9(R, c, a);
        }
    __syncthreads();

    // ---- layer 1 MFMA: K=576, 4 coltiles ----
    acc0 = (float4v){0.f, 0.f, 0.f, 0.f}; acc1 = (float4v){0.f, 0.f, 0.f, 0.f};
    mfma_layer<S1c, T1c>(WH1, WL1, w, lane, r15, kg, swA, pb, acc0, acc1);
    __syncthreads();

    // ---- layer-2 A-panel ----
#pragma unroll
    for (int m = 0; m < 2; ++m)
#pragma unroll
        for (int reg = 0; reg < 4; ++reg) {
            int R = 16 * m + 4 * kg + reg;
            int c = 16 * w + r15;
            float a[9]; feats(m == 0 ? acc0[reg] : acc1[reg], a);
            write9(R, c, a);
        }
    __syncthreads();

    // ---- layer 2 MFMA: K=576, 2 coltiles (waves 0,1) ----
    acc0 = (float4v){0.f, 0.f, 0.f, 0.f}; acc1 = (float4v){0.f, 0.f, 0.f, 0.f};
    if (w < 2)
        mfma_layer<S2c, T2c>(WH2, WL2, w, lane, r15, kg, swA, pb, acc0, acc1);
    __syncthreads();

    // ---- store: acc -> LDS [c][R] fp32, then coalesced global write ----
    float* fp = (float*)pb;
    if (w < 2) {
#pragma unroll
        for (int m = 0; m < 2; ++m)
#pragma unroll
            for (int reg = 0; reg < 4; ++reg) {
                int R = 16 * m + 4 * kg + reg;
                int c = 16 * w + r15;
                if (c < D3) fp[c * 32 + R] = (m == 0 ? acc0[reg] : acc1[reg]);
            }
    }
    __syncthreads();
#pragma unroll
    for (int q = 0; q < 3; ++q) {                     // 768 floats = 24 cols x 32 rows
        int idx = tid + BLK * q;
        int c = idx >> 5, R = idx & 31;
        Y[(b * D3 + c) * HWP + p0 + R] = fp[idx];
    }
}

extern "C" void kernel_launch(void* const* d_in, const int* in_sizes, int n_in,
                              void* d_out, int out_size, void* d_ws, size_t ws_size,
                              hipStream_t stream) {
    const float* X     = (const float*)d_in[0];
    const float* grid0 = (const float*)d_in[1];
    const float* coef0 = (const float*)d_in[2];
    const float* sb0   = (const float*)d_in[3];
    const float* ss0   = (const float*)d_in[4];
    const float* coef1 = (const float*)d_in[6];
    const float* sb1   = (const float*)d_in[7];
    const float* ss1   = (const float*)d_in[8];
    const float* coef2 = (const float*)d_in[10];
    const float* sb2   = (const float*)d_in[11];
    const float* ss2   = (const float*)d_in[12];
    float* Yout = (float*)d_out;

    unsigned short* W = (unsigned short*)d_ws;
    if (ws_size < WBYTES) {
        void* sym = nullptr;
        hipGetSymbolAddress(&sym, HIP_SYMBOL(g_Wfb));
        W = (unsigned short*)sym;
    }

    hipLaunchKernelGGL(pack_w, dim3((WE_ALL + 255) / 256), dim3(256), 0, stream, W,
                       coef0, sb0, ss0, coef1, sb1, ss1, coef2, sb2, ss2);
    hipLaunchKernelGGL(kan_mfma, dim3(NROWS / ROWS), dim3(BLK), 0, stream,
                       X, Yout, grid0, W);
}

// Round 6
// 141.245 us; speedup vs baseline: 3.4066x; 1.7106x over previous
//
#include <hip/hip_runtime.h>
#include <hip/hip_bf16.h>
#include <math.h>

// ---- problem constants ----
#define D0 12
#define D1 64
#define D2 64
#define D3 24
#define HWP 4096
#define NROWS (32 * HWP)

#define ROWS 32            // rows per block
#define BLK 256            // threads (4 waves)

// K dims (k = 9*i + g), padded to multiple of 32
#define K0 128             // real 108
#define K1 576
#define K2 576
#define S0c (K0/32)        // 4 k-steps
#define S1c (K1/32)        // 18
#define S2c (K2/32)        // 18
#define T0c 4              // col tiles of 16 (64 cols)
#define T1c 4
#define T2c 2              // 32 cols (24 real)

// packed-W element counts (ushort) per panel, fragment-linear layout
#define WE0 (S0c*T0c*64*8) //  8192
#define WE1 (S1c*T1c*64*8) // 36864
#define WE2 (S2c*T2c*64*8) // 18432
#define WE_ALL (WE0+WE1+WE2)          // 63488 per panel (hi, lo)
#define WBYTES (2*WE_ALL*sizeof(unsigned short))  // 253952 B

typedef __attribute__((ext_vector_type(8))) short short8;
typedef __attribute__((ext_vector_type(4))) float float4v;

__device__ __align__(16) unsigned short g_Wfb[2 * WE_ALL];  // fallback if ws too small

// exact-RNE manual path (pack kernel only; needs hi/lo round-trip)
__device__ __forceinline__ unsigned short f2bf(float f) {
    unsigned int b = __float_as_uint(f);
    unsigned int r = (b + 0x7FFFu + ((b >> 16) & 1u)) >> 16;   // RNE
    return (unsigned short)r;
}
__device__ __forceinline__ float bf2f(unsigned short u) {
    return __uint_as_float(((unsigned int)u) << 16);
}
// hot-path conversion: compiler-emitted HW cvt (RNE)
__device__ __forceinline__ unsigned short f2bf_fast(float f) {
    __hip_bfloat16 h = __float2bfloat16(f);
    return reinterpret_cast<unsigned short&>(h);
}

// ---- pack kernel: W[(9i+g)][o] -> bf16 hi/lo in MFMA-B fragment-linear layout ----
// elem index within a layer: ((s*T + t)*64 + lane)*8 + j ; k = 32s + 8*(lane>>4) + j ; o = 16t + (lane&15)
__global__ void pack_w(unsigned short* __restrict__ Wpk,
                       const float* __restrict__ c0, const float* __restrict__ b0, const float* __restrict__ s0_,
                       const float* __restrict__ c1, const float* __restrict__ b1, const float* __restrict__ s1_,
                       const float* __restrict__ c2, const float* __restrict__ b2, const float* __restrict__ s2_) {
    int idx = blockIdx.x * 256 + threadIdx.x;
    if (idx >= WE_ALL) return;
    int base, T, in, out;
    const float *cf, *sb, *ss;
    if (idx < WE0)            { base = idx;             T = T0c; in = D0; out = D1; cf = c0; sb = b0; ss = s0_; }
    else if (idx < WE0 + WE1) { base = idx - WE0;       T = T1c; in = D1; out = D2; cf = c1; sb = b1; ss = s1_; }
    else                      { base = idx - WE0 - WE1; T = T2c; in = D2; out = D3; cf = c2; sb = b2; ss = s2_; }
    int j  = base & 7;
    int l  = (base >> 3) & 63;
    int st = base >> 9;
    int t  = st % T;
    int s  = st / T;
    int k  = 32 * s + 8 * (l >> 4) + j;
    int o  = 16 * t + (l & 15);
    float w = 0.0f;
    int i = k / 9, g = k % 9;
    if (i < in && o < out)
        w = (g < 8) ? cf[(i * out + o) * 8 + g] * ss[i * out + o] : sb[i * out + o];
    unsigned short hi = f2bf(w);
    unsigned short lo = f2bf(w - bf2f(hi));
    Wpk[idx] = hi;
    Wpk[idx + WE_ALL] = lo;
}

// ---- main fused kernel ----
__device__ __forceinline__ float sgpr(float x) {
    return __uint_as_float(__builtin_amdgcn_readfirstlane(__float_as_uint(x)));
}

#define MFMA16(a, b, c) __builtin_amdgcn_mfma_f32_16x16x32_bf16((a), (b), (c), 0, 0, 0)

// A-fragment read from swizzled LDS panel: row R = 16m + r15, k0 = 32s + 16*kg bytes
#define LDA(m, s) (*(const short8*)(pb + ((((16*(m) + r15) * 1152) + 64*(s) + 16*kg) ^ swA)))

// depth-2 W prefetch (VGPR pressure: keep only 2 hi/lo pairs live)
template <int NS, int T>
__device__ __forceinline__ void mfma_layer(const unsigned short* __restrict__ WH,
                                           const unsigned short* __restrict__ WL,
                                           int w, int lane, int r15, int kg, int swA,
                                           const char* pb, float4v& acc0, float4v& acc1) {
    short8 wh[NS], wl[NS];
#pragma unroll
    for (int s = 0; s < (NS < 2 ? NS : 2); ++s) {
        wh[s] = *(const short8*)(WH + (((size_t)(s * T + w) * 64 + lane) * 8));
        wl[s] = *(const short8*)(WL + (((size_t)(s * T + w) * 64 + lane) * 8));
    }
#pragma unroll
    for (int s = 0; s < NS; ++s) {
        if (s + 2 < NS) {
            wh[s + 2] = *(const short8*)(WH + (((size_t)((s + 2) * T + w) * 64 + lane) * 8));
            wl[s + 2] = *(const short8*)(WL + (((size_t)((s + 2) * T + w) * 64 + lane) * 8));
        }
        short8 a0 = LDA(0, s);
        short8 a1 = LDA(1, s);
        acc0 = MFMA16(a0, wh[s], acc0);
        acc0 = MFMA16(a0, wl[s], acc0);
        acc1 = MFMA16(a1, wh[s], acc1);
        acc1 = MFMA16(a1, wl[s], acc1);
    }
}

__global__ __launch_bounds__(BLK, 4) void kan_mfma(const float* __restrict__ X,
                                                   float* __restrict__ Y,
                                                   const float* __restrict__ grid,
                                                   const unsigned short* __restrict__ Wpk) {
    __shared__ __align__(16) unsigned short panel[ROWS * 576];   // 36864 B
    char* pb = (char*)&panel[0];

    const int tid  = threadIdx.x;
    const int lane = tid & 63;
    const int w    = tid >> 6;        // wave id = coltile
    const int r15  = lane & 15;
    const int kg   = lane >> 4;       // 0..3
    const int swA  = (r15 & 7) << 4;  // read-side XOR swizzle (R&7 == r15&7 for R=16m+r15)

    const int b  = blockIdx.x >> 7;          // image
    const int p0 = (blockIdx.x & 127) * 32;  // pixel base for this block's 32 rows

    // uniform grid: only g0 and 1/h needed (all knot spacings equal)
    const float g0   = sgpr(grid[0]);
    const float invh = sgpr(1.0f / (grid[4] - grid[3]));

    // Direct uniform cubic B-spline: only 4 basis funcs nonzero at v.
    // cell c = floor((v-g0)/h) in [0,10]; u = local coord; slot j = c-3+d
    // gets piece: P[0]=(1-u)^3/6 ... P[3]=u^3/6. Outside [g0,g11): all zero.
    auto writeEval = [&](int R, int i, float v) {
        float t = (v - g0) * invh;
        float cf = floorf(t);
        int c = (int)cf;
        float u = t - cf;
        bool inr = (t >= 0.0f) && (c <= 10);
        float u2 = u * u, u3 = u2 * u;
        float omu = 1.0f - u;
        float P[4];
        P[0] = omu * omu * omu * (1.0f / 6.0f);
        P[1] = (4.0f / 6.0f) + (0.5f * u3 - u2);
        P[2] = (1.0f / 6.0f) + 0.5f * (u + u2 - u3);
        P[3] = u3 * (1.0f / 6.0f);
        int sw = (R & 7) << 4;
        int rb = R * 1152 + 18 * i;
        if (inr) {
#pragma unroll
            for (int d = 0; d < 4; ++d) {
                int j = c - 3 + d;
                if ((unsigned)j < 8u)
                    *(unsigned short*)(pb + ((rb + 2 * j) ^ sw)) = f2bf_fast(P[d]);
            }
        }
        float s = v / (1.0f + __expf(-v));                 // silu -> slot 8
        *(unsigned short*)(pb + ((rb + 16) ^ sw)) = f2bf_fast(s);
    };

    // conflict-free full-panel zero (zeros are swizzle-invariant)
    auto zeroPanel = [&] {
        float4v z = {0.f, 0.f, 0.f, 0.f};
#pragma unroll
        for (int q = 0; q < 9; ++q)
            *(float4v*)(pb + (tid * 16 + q * 4096)) = z;
    };

    const unsigned short* WH0 = Wpk;
    const unsigned short* WH1 = Wpk + WE0;
    const unsigned short* WH2 = Wpk + WE0 + WE1;
    const unsigned short* WL0 = Wpk + WE_ALL;
    const unsigned short* WL1 = Wpk + WE_ALL + WE0;
    const unsigned short* WL2 = Wpk + WE_ALL + WE0 + WE1;

    // ---- phase 0: layer-0 A-panel from X (32 rows x 12 feats = 384 evals) ----
    zeroPanel();
    __syncthreads();
    {
        int R = tid & 31, i = tid >> 5;
        writeEval(R, i, X[(b * D0 + i) * HWP + p0 + R]);
        if (tid < 128) {
            int R2 = (tid + 256) & 31, i2 = (tid + 256) >> 5;
            writeEval(R2, i2, X[(b * D0 + i2) * HWP + p0 + R2]);
        }
    }
    __syncthreads();

    // ---- layer 0 MFMA: K=128, 4 coltiles ----
    float4v acc0 = {0.f, 0.f, 0.f, 0.f}, acc1 = {0.f, 0.f, 0.f, 0.f};
    mfma_layer<S0c, T0c>(WH0, WL0, w, lane, r15, kg, swA, pb, acc0, acc1);
    __syncthreads();

    // ---- layer-1 A-panel from acc (each lane: 2 tiles x 4 regs = 8 evals) ----
    zeroPanel();
    __syncthreads();
#pragma unroll
    for (int m = 0; m < 2; ++m)
#pragma unroll
        for (int reg = 0; reg < 4; ++reg) {
            int R = 16 * m + 4 * kg + reg;            // C/D row mapping (m89)
            int c = 16 * w + r15;                     // C/D col mapping
            writeEval(R, c, m == 0 ? acc0[reg] : acc1[reg]);
        }
    __syncthreads();

    // ---- layer 1 MFMA: K=576, 4 coltiles ----
    acc0 = (float4v){0.f, 0.f, 0.f, 0.f}; acc1 = (float4v){0.f, 0.f, 0.f, 0.f};
    mfma_layer<S1c, T1c>(WH1, WL1, w, lane, r15, kg, swA, pb, acc0, acc1);
    __syncthreads();

    // ---- layer-2 A-panel ----
    zeroPanel();
    __syncthreads();
#pragma unroll
    for (int m = 0; m < 2; ++m)
#pragma unroll
        for (int reg = 0; reg < 4; ++reg) {
            int R = 16 * m + 4 * kg + reg;
            int c = 16 * w + r15;
            writeEval(R, c, m == 0 ? acc0[reg] : acc1[reg]);
        }
    __syncthreads();

    // ---- layer 2 MFMA: K=576, 2 coltiles (waves 0,1) ----
    acc0 = (float4v){0.f, 0.f, 0.f, 0.f}; acc1 = (float4v){0.f, 0.f, 0.f, 0.f};
    if (w < 2)
        mfma_layer<S2c, T2c>(WH2, WL2, w, lane, r15, kg, swA, pb, acc0, acc1);
    __syncthreads();

    // ---- store: acc -> LDS [c][R] fp32, then coalesced global write ----
    float* fp = (float*)pb;
    if (w < 2) {
#pragma unroll
        for (int m = 0; m < 2; ++m)
#pragma unroll
            for (int reg = 0; reg < 4; ++reg) {
                int R = 16 * m + 4 * kg + reg;
                int c = 16 * w + r15;
                if (c < D3) fp[c * 32 + R] = (m == 0 ? acc0[reg] : acc1[reg]);
            }
    }
    __syncthreads();
#pragma unroll
    for (int q = 0; q < 3; ++q) {                     // 768 floats = 24 cols x 32 rows
        int idx = tid + BLK * q;
        int c = idx >> 5, R = idx & 31;
        Y[(b * D3 + c) * HWP + p0 + R] = fp[idx];
    }
}

extern "C" void kernel_launch(void* const* d_in, const int* in_sizes, int n_in,
                              void* d_out, int out_size, void* d_ws, size_t ws_size,
                              hipStream_t stream) {
    const float* X     = (const float*)d_in[0];
    const float* grid0 = (const float*)d_in[1];
    const float* coef0 = (const float*)d_in[2];
    const float* sb0   = (const float*)d_in[3];
    const float* ss0   = (const float*)d_in[4];
    const float* coef1 = (const float*)d_in[6];
    const float* sb1   = (const float*)d_in[7];
    const float* ss1   = (const float*)d_in[8];
    const float* coef2 = (const float*)d_in[10];
    const float* sb2   = (const float*)d_in[11];
    const float* ss2   = (const float*)d_in[12];
    float* Yout = (float*)d_out;

    unsigned short* W = (unsigned short*)d_ws;
    if (ws_size < WBYTES) {
        void* sym = nullptr;
        hipGetSymbolAddress(&sym, HIP_SYMBOL(g_Wfb));
        W = (unsigned short*)sym;
    }

    hipLaunchKernelGGL(pack_w, dim3((WE_ALL + 255) / 256), dim3(256), 0, stream, W,
                       coef0, sb0, ss0, coef1, sb1, ss1, coef2, sb2, ss2);
    hipLaunchKernelGGL(kan_mfma, dim3(NROWS / ROWS), dim3(BLK), 0, stream,
                       X, Yout, grid0, W);
}

// Round 14
// 139.823 us; speedup vs baseline: 3.4412x; 1.0102x over previous
//
#include <hip/hip_runtime.h>
#include <hip/hip_bf16.h>
#include <math.h>

// ---- problem constants ----
#define D0 12
#define D1 64
#define D2 64
#define D3 24
#define HWP 4096
#define NROWS (32 * HWP)

#define ROWS 32            // rows per block
#define BLK 256            // threads (4 waves)

// K dims: k = 8*i + d (spline slot d of feature i), k = 8*Din + i (silu)
#define K0 128             // real 108 (96 spline + 12 silu), pad to 128
#define K1 576             // 512 spline + 64 silu, exact
#define K2 576
#define S0c (K0/32)        // 4 k-steps
#define S1c (K1/32)        // 18
#define S2c (K2/32)        // 18
#define T0c 4              // col tiles of 16 (64 cols)
#define T1c 4
#define T2c 2              // 32 cols (24 real)

// packed-W element counts (ushort) per panel, fragment-linear layout
#define WE0 (S0c*T0c*64*8) //  8192
#define WE1 (S1c*T1c*64*8) // 36864
#define WE2 (S2c*T2c*64*8) // 18432
#define WE_ALL (WE0+WE1+WE2)          // 63488 per panel (hi, lo)
#define WBYTES (2*WE_ALL*sizeof(unsigned short))  // 253952 B

typedef __attribute__((ext_vector_type(8))) short short8;
typedef __attribute__((ext_vector_type(4))) float float4v;
typedef __attribute__((ext_vector_type(2))) unsigned long long ull2;

__device__ __align__(16) unsigned short g_Wfb[2 * WE_ALL];  // fallback if ws too small

// exact-RNE manual path (pack kernel only; needs hi/lo round-trip)
__device__ __forceinline__ unsigned short f2bf(float f) {
    unsigned int b = __float_as_uint(f);
    unsigned int r = (b + 0x7FFFu + ((b >> 16) & 1u)) >> 16;   // RNE
    return (unsigned short)r;
}
__device__ __forceinline__ float bf2f(unsigned short u) {
    return __uint_as_float(((unsigned int)u) << 16);
}
__device__ __forceinline__ unsigned short f2bf_fast(float f) {
    __hip_bfloat16 h = __float2bfloat16(f);
    return reinterpret_cast<unsigned short&>(h);
}

// ---- pack kernel: k<8*Din: coef[i=k>>3][o][g=k&7]*ss; k in [8Din,9Din): sb; else 0
// frag elem: ((s*T + t)*64 + l)*8 + j ; k = 32s + 8*(l>>4) + j ; o = 16t + (l&15)
__global__ void pack_w(unsigned short* __restrict__ Wpk,
                       const float* __restrict__ c0, const float* __restrict__ b0, const float* __restrict__ s0_,
                       const float* __restrict__ c1, const float* __restrict__ b1, const float* __restrict__ s1_,
                       const float* __restrict__ c2, const float* __restrict__ b2, const float* __restrict__ s2_) {
    int idx = blockIdx.x * 256 + threadIdx.x;
    if (idx >= WE_ALL) return;
    int base, T, in, out;
    const float *cf, *sb, *ss;
    if (idx < WE0)            { base = idx;             T = T0c; in = D0; out = D1; cf = c0; sb = b0; ss = s0_; }
    else if (idx < WE0 + WE1) { base = idx - WE0;       T = T1c; in = D1; out = D2; cf = c1; sb = b1; ss = s1_; }
    else                      { base = idx - WE0 - WE1; T = T2c; in = D2; out = D3; cf = c2; sb = b2; ss = s2_; }
    int j  = base & 7;
    int l  = (base >> 3) & 63;
    int st = base >> 9;
    int t  = st % T;
    int s  = st / T;
    int k  = 32 * s + 8 * (l >> 4) + j;
    int o  = 16 * t + (l & 15);
    float w = 0.0f;
    if (o < out) {
        if (k < 8 * in) {
            int i = k >> 3, g = k & 7;
            w = cf[(i * out + o) * 8 + g] * ss[i * out + o];
        } else if (k < 9 * in) {
            int i = k - 8 * in;
            w = sb[i * out + o];
        }
    }
    unsigned short hi = f2bf(w);
    unsigned short lo = f2bf(w - bf2f(hi));
    Wpk[idx] = hi;
    Wpk[idx + WE_ALL] = lo;
}

// ---- main fused kernel ----
__device__ __forceinline__ float sgpr(float x) {
    return __uint_as_float(__builtin_amdgcn_readfirstlane(__float_as_uint(x)));
}

#define MFMA16(a, b, c) __builtin_amdgcn_mfma_f32_16x16x32_bf16((a), (b), (c), 0, 0, 0)

// A-fragment read from swizzled LDS panel: row R = 16m + r15, k0 = 32s + 16*kg bytes
#define LDA(m, s) (*(const short8*)(pb + ((((16*(m) + r15) * 1152) + 64*(s) + 16*kg) ^ swA)))

// depth-2 W prefetch; 4 independent acc chains (hi/lo split), setprio around MFMA loop
template <int NS, int T>
__device__ __forceinline__ void mfma_layer(const unsigned short* __restrict__ WH,
                                           const unsigned short* __restrict__ WL,
                                           int w, int lane, int r15, int kg, int swA,
                                           const char* pb, float4v& o0, float4v& o1) {
    short8 wh[NS], wl[NS];
#pragma unroll
    for (int s = 0; s < (NS < 2 ? NS : 2); ++s) {
        wh[s] = *(const short8*)(WH + (((size_t)(s * T + w) * 64 + lane) * 8));
        wl[s] = *(const short8*)(WL + (((size_t)(s * T + w) * 64 + lane) * 8));
    }
    float4v a0h = {0.f,0.f,0.f,0.f}, a0l = {0.f,0.f,0.f,0.f};
    float4v a1h = {0.f,0.f,0.f,0.f}, a1l = {0.f,0.f,0.f,0.f};
    __builtin_amdgcn_s_setprio(1);
#pragma unroll
    for (int s = 0; s < NS; ++s) {
        if (s + 2 < NS) {
            wh[s + 2] = *(const short8*)(WH + (((size_t)((s + 2) * T + w) * 64 + lane) * 8));
            wl[s + 2] = *(const short8*)(WL + (((size_t)((s + 2) * T + w) * 64 + lane) * 8));
        }
        short8 A0 = LDA(0, s);
        short8 A1 = LDA(1, s);
        a0h = MFMA16(A0, wh[s], a0h);
        a0l = MFMA16(A0, wl[s], a0l);
        a1h = MFMA16(A1, wh[s], a1h);
        a1l = MFMA16(A1, wl[s], a1l);
    }
    __builtin_amdgcn_s_setprio(0);
    o0 = a0h + a0l;
    o1 = a1h + a1l;
}

__global__ __launch_bounds__(BLK, 4) void kan_mfma(const float* __restrict__ X,
                                                   float* __restrict__ Y,
                                                   const float* __restrict__ grid,
                                                   const unsigned short* __restrict__ Wpk) {
    __shared__ __align__(16) unsigned short panel[ROWS * 576];   // 36864 B
    char* pb = (char*)&panel[0];

    const int tid  = threadIdx.x;
    const int lane = tid & 63;
    const int w    = tid >> 6;        // wave id = coltile
    const int r15  = lane & 15;
    const int kg   = lane >> 4;       // 0..3
    const int swA  = (r15 & 7) << 4;  // read-side XOR swizzle (R&7 == r15&7 for R=16m+r15)

    const int b  = blockIdx.x >> 7;          // image
    const int p0 = (blockIdx.x & 127) * 32;  // pixel base for this block's 32 rows

    // uniform grid: only g0 and 1/h needed
    const float g0   = sgpr(grid[0]);
    const float invh = sgpr(1.0f / (grid[4] - grid[3]));

    // Dense uniform cubic B-spline eval: pieces P0..P3 occupy slots c-3..c.
    // Dense 8-slot row built by 128-bit shift of packed bf16 quad; one b128 write.
    // Scalar casts (not inline-asm cvt_pk) per m240: compiler schedules/fuses better.
    auto writeEval = [&](int R, int i, float v, int siluBase) {
        float t = (v - g0) * invh;
        float cfl = floorf(t);
        int c = (int)cfl;
        float u = t - cfl;
        float u2 = u * u, u3 = u2 * u, omu = 1.0f - u;
        float P0f = omu * omu * omu * (1.0f / 6.0f);
        float P1f = (4.0f / 6.0f) + (0.5f * u3 - u2);
        float P2f = (1.0f / 6.0f) + 0.5f * (u + u2 - u3);
        float P3f = u3 * (1.0f / 6.0f);
        unsigned int lo32 = ((unsigned int)f2bf_fast(P1f) << 16) | f2bf_fast(P0f);
        unsigned int hi32 = ((unsigned int)f2bf_fast(P3f) << 16) | f2bf_fast(P2f);
        unsigned long long p64 = ((unsigned long long)hi32 << 32) | lo32;
        bool inr = (t >= 0.0f) && (c <= 10);
        int cc = inr ? c : 3;                  // safe shift domain; masked below
        int sh = 16 * cc - 48;                 // in [-48, 112]
        unsigned long long l  = p64 << (sh & 63);
        unsigned long long rr = p64 >> ((-sh) & 63);
        unsigned long long h  = p64 >> ((64 - sh) & 63);
        unsigned long long h2 = p64 << ((sh - 64) & 63);
        unsigned long long r0 = sh < 0 ? rr : (sh < 64 ? l : 0ull);
        unsigned long long r1 = sh >= 64 ? h2 : (sh > 0 ? h : 0ull);
        if (!inr) { r0 = 0ull; r1 = 0ull; }
        int sw = (R & 7) << 4;
        ull2 o2; o2[0] = r0; o2[1] = r1;
        *(ull2*)(pb + ((R * 1152 + 16 * i) ^ sw)) = o2;        // 16B-aligned; swizzle keeps alignment
        float s = v / (1.0f + __expf(-v));                     // silu
        *(unsigned short*)(pb + ((R * 1152 + siluBase + 2 * i) ^ sw)) = f2bf_fast(s);
    };

    const unsigned short* WH0 = Wpk;
    const unsigned short* WH1 = Wpk + WE0;
    const unsigned short* WH2 = Wpk + WE0 + WE1;
    const unsigned short* WL0 = Wpk + WE_ALL;
    const unsigned short* WL1 = Wpk + WE_ALL + WE0;
    const unsigned short* WL2 = Wpk + WE_ALL + WE0 + WE1;

    // ---- phase 0: L0 pad zero (logical bytes [216,256) per row) + panel build ----
    if (tid < 96) {
        int r = tid / 3, part = tid % 3;
        int sw = (r & 7) << 4;
        char* base = pb + r * 1152;
        if (part == 0) *(unsigned long long*)(base + (216 ^ sw)) = 0ull;
        else if (part == 1) { ull2 z; z[0] = 0; z[1] = 0; *(ull2*)(base + (224 ^ sw)) = z; }
        else                { ull2 z; z[0] = 0; z[1] = 0; *(ull2*)(base + (240 ^ sw)) = z; }
    }
    {
        int R = tid & 31, i = tid >> 5;
        writeEval(R, i, X[(b * D0 + i) * HWP + p0 + R], 192);
        if (tid < 128) {
            int R2 = (tid + 256) & 31, i2 = (tid + 256) >> 5;
            writeEval(R2, i2, X[(b * D0 + i2) * HWP + p0 + R2], 192);
        }
    }
    __syncthreads();

    // ---- layer 0 MFMA ----
    float4v acc0, acc1;
    mfma_layer<S0c, T0c>(WH0, WL0, w, lane, r15, kg, swA, pb, acc0, acc1);
    __syncthreads();

    // ---- layer-1 panel build (each lane: 2 tiles x 4 regs = 8 evals) ----
#pragma unroll
    for (int m = 0; m < 2; ++m)
#pragma unroll
        for (int reg = 0; reg < 4; ++reg) {
            int R = 16 * m + 4 * kg + reg;            // C/D row mapping (m89)
            int ccol = 16 * w + r15;                  // C/D col mapping
            writeEval(R, ccol, m == 0 ? acc0[reg] : acc1[reg], 1024);
        }
    __syncthreads();

    // ---- layer 1 MFMA ----
    mfma_layer<S1c, T1c>(WH1, WL1, w, lane, r15, kg, swA, pb, acc0, acc1);
    __syncthreads();

    // ---- layer-2 panel build ----
#pragma unroll
    for (int m = 0; m < 2; ++m)
#pragma unroll
        for (int reg = 0; reg < 4; ++reg) {
            int R = 16 * m + 4 * kg + reg;
            int ccol = 16 * w + r15;
            writeEval(R, ccol, m == 0 ? acc0[reg] : acc1[reg], 1024);
        }
    __syncthreads();

    // ---- layer 2 MFMA (2 coltiles, waves 0,1) ----
    acc0 = (float4v){0.f, 0.f, 0.f, 0.f}; acc1 = (float4v){0.f, 0.f, 0.f, 0.f};
    if (w < 2)
        mfma_layer<S2c, T2c>(WH2, WL2, w, lane, r15, kg, swA, pb, acc0, acc1);
    __syncthreads();

    // ---- store: acc -> LDS [c][R] fp32 (pad 33 kills bank conflict), coalesced write ----
    float* fp = (float*)pb;
    if (w < 2) {
#pragma unroll
        for (int m = 0; m < 2; ++m)
#pragma unroll
            for (int reg = 0; reg < 4; ++reg) {
                int R = 16 * m + 4 * kg + reg;
                int ccol = 16 * w + r15;
                if (ccol < D3) fp[ccol * 33 + R] = (m == 0 ? acc0[reg] : acc1[reg]);
            }
    }
    __syncthreads();
#pragma unroll
    for (int q = 0; q < 3; ++q) {                     // 768 floats = 24 cols x 32 rows
        int idx = tid + BLK * q;
        int ccol = idx >> 5, R = idx & 31;
        Y[(b * D3 + ccol) * HWP + p0 + R] = fp[ccol * 33 + R];
    }
}

extern "C" void kernel_launch(void* const* d_in, const int* in_sizes, int n_in,
                              void* d_out, int out_size, void* d_ws, size_t ws_size,
                              hipStream_t stream) {
    const float* X     = (const float*)d_in[0];
    const float* grid0 = (const float*)d_in[1];
    const float* coef0 = (const float*)d_in[2];
    const float* sb0   = (const float*)d_in[3];
    const float* ss0   = (const float*)d_in[4];
    const float* coef1 = (const float*)d_in[6];
    const float* sb1   = (const float*)d_in[7];
    const float* ss1   = (const float*)d_in[8];
    const float* coef2 = (const float*)d_in[10];
    const float* sb2   = (const float*)d_in[11];
    const float* ss2   = (const float*)d_in[12];
    float* Yout = (float*)d_out;

    unsigned short* W = (unsigned short*)d_ws;
    if (ws_size < WBYTES) {
        void* sym = nullptr;
        hipGetSymbolAddress(&sym, HIP_SYMBOL(g_Wfb));
        W = (unsigned short*)sym;
    }

    hipLaunchKernelGGL(pack_w, dim3((WE_ALL + 255) / 256), dim3(256), 0, stream, W,
                       coef0, sb0, ss0, coef1, sb1, ss1, coef2, sb2, ss2);
    hipLaunchKernelGGL(kan_mfma, dim3(NROWS / ROWS), dim3(BLK), 0, stream,
                       X, Yout, grid0, W);
}

// Round 15
// 138.602 us; speedup vs baseline: 3.4715x; 1.0088x over previous
//
#include <hip/hip_runtime.h>
#include <hip/hip_bf16.h>
#include <math.h>

// ---- problem constants ----
#define D0 12
#define D1 64
#define D2 64
#define D3 24
#define HWP 4096
#define NROWS (32 * HWP)

#define ROWS 32            // rows per block
#define BLK 256            // threads (4 waves)
#define PF 5               // W prefetch depth (R15: 2 -> 5, targets ~200cy L2 latency)

// K dims: k = 8*i + d (spline slot d of feature i), k = 8*Din + i (silu)
#define K0 128             // real 108 (96 spline + 12 silu), pad to 128
#define K1 576             // 512 spline + 64 silu, exact
#define K2 576
#define S0c (K0/32)        // 4 k-steps
#define S1c (K1/32)        // 18
#define S2c (K2/32)        // 18
#define T0c 4              // col tiles of 16 (64 cols)
#define T1c 4
#define T2c 2              // 32 cols (24 real)

// packed-W element counts (ushort) per panel, fragment-linear layout
#define WE0 (S0c*T0c*64*8) //  8192
#define WE1 (S1c*T1c*64*8) // 36864
#define WE2 (S2c*T2c*64*8) // 18432
#define WE_ALL (WE0+WE1+WE2)          // 63488 per panel (hi, lo)
#define WBYTES (2*WE_ALL*sizeof(unsigned short))  // 253952 B

typedef __attribute__((ext_vector_type(8))) short short8;
typedef __attribute__((ext_vector_type(4))) float float4v;
typedef __attribute__((ext_vector_type(2))) unsigned long long ull2;

__device__ __align__(16) unsigned short g_Wfb[2 * WE_ALL];  // fallback if ws too small

// exact-RNE manual path (pack kernel only; needs hi/lo round-trip)
__device__ __forceinline__ unsigned short f2bf(float f) {
    unsigned int b = __float_as_uint(f);
    unsigned int r = (b + 0x7FFFu + ((b >> 16) & 1u)) >> 16;   // RNE
    return (unsigned short)r;
}
__device__ __forceinline__ float bf2f(unsigned short u) {
    return __uint_as_float(((unsigned int)u) << 16);
}
__device__ __forceinline__ unsigned short f2bf_fast(float f) {
    __hip_bfloat16 h = __float2bfloat16(f);
    return reinterpret_cast<unsigned short&>(h);
}

// ---- pack kernel: k<8*Din: coef[i=k>>3][o][g=k&7]*ss; k in [8Din,9Din): sb; else 0
// frag elem: ((s*T + t)*64 + l)*8 + j ; k = 32s + 8*(l>>4) + j ; o = 16t + (l&15)
__global__ void pack_w(unsigned short* __restrict__ Wpk,
                       const float* __restrict__ c0, const float* __restrict__ b0, const float* __restrict__ s0_,
                       const float* __restrict__ c1, const float* __restrict__ b1, const float* __restrict__ s1_,
                       const float* __restrict__ c2, const float* __restrict__ b2, const float* __restrict__ s2_) {
    int idx = blockIdx.x * 256 + threadIdx.x;
    if (idx >= WE_ALL) return;
    int base, T, in, out;
    const float *cf, *sb, *ss;
    if (idx < WE0)            { base = idx;             T = T0c; in = D0; out = D1; cf = c0; sb = b0; ss = s0_; }
    else if (idx < WE0 + WE1) { base = idx - WE0;       T = T1c; in = D1; out = D2; cf = c1; sb = b1; ss = s1_; }
    else                      { base = idx - WE0 - WE1; T = T2c; in = D2; out = D3; cf = c2; sb = b2; ss = s2_; }
    int j  = base & 7;
    int l  = (base >> 3) & 63;
    int st = base >> 9;
    int t  = st % T;
    int s  = st / T;
    int k  = 32 * s + 8 * (l >> 4) + j;
    int o  = 16 * t + (l & 15);
    float w = 0.0f;
    if (o < out) {
        if (k < 8 * in) {
            int i = k >> 3, g = k & 7;
            w = cf[(i * out + o) * 8 + g] * ss[i * out + o];
        } else if (k < 9 * in) {
            int i = k - 8 * in;
            w = sb[i * out + o];
        }
    }
    unsigned short hi = f2bf(w);
    unsigned short lo = f2bf(w - bf2f(hi));
    Wpk[idx] = hi;
    Wpk[idx + WE_ALL] = lo;
}

// ---- main fused kernel ----
__device__ __forceinline__ float sgpr(float x) {
    return __uint_as_float(__builtin_amdgcn_readfirstlane(__float_as_uint(x)));
}

#define MFMA16(a, b, c) __builtin_amdgcn_mfma_f32_16x16x32_bf16((a), (b), (c), 0, 0, 0)

// A-fragment read from swizzled LDS panel: row R = 16m + r15, k0 = 32s + 16*kg bytes
#define LDA(m, s) (*(const short8*)(pb + ((((16*(m) + r15) * 1152) + 64*(s) + 16*kg) ^ swA)))

// depth-PF W prefetch; 4 independent acc chains (hi/lo split), setprio around MFMA loop
template <int NS, int T>
__device__ __forceinline__ void mfma_layer(const unsigned short* __restrict__ WH,
                                           const unsigned short* __restrict__ WL,
                                           int w, int lane, int r15, int kg, int swA,
                                           const char* pb, float4v& o0, float4v& o1) {
    short8 wh[NS], wl[NS];
#pragma unroll
    for (int s = 0; s < (NS < PF ? NS : PF); ++s) {
        wh[s] = *(const short8*)(WH + (((size_t)(s * T + w) * 64 + lane) * 8));
        wl[s] = *(const short8*)(WL + (((size_t)(s * T + w) * 64 + lane) * 8));
    }
    float4v a0h = {0.f,0.f,0.f,0.f}, a0l = {0.f,0.f,0.f,0.f};
    float4v a1h = {0.f,0.f,0.f,0.f}, a1l = {0.f,0.f,0.f,0.f};
    __builtin_amdgcn_s_setprio(1);
#pragma unroll
    for (int s = 0; s < NS; ++s) {
        if (s + PF < NS) {
            wh[s + PF] = *(const short8*)(WH + (((size_t)((s + PF) * T + w) * 64 + lane) * 8));
            wl[s + PF] = *(const short8*)(WL + (((size_t)((s + PF) * T + w) * 64 + lane) * 8));
        }
        short8 A0 = LDA(0, s);
        short8 A1 = LDA(1, s);
        a0h = MFMA16(A0, wh[s], a0h);
        a0l = MFMA16(A0, wl[s], a0l);
        a1h = MFMA16(A1, wh[s], a1h);
        a1l = MFMA16(A1, wl[s], a1l);
    }
    __builtin_amdgcn_s_setprio(0);
    o0 = a0h + a0l;
    o1 = a1h + a1l;
}

__global__ __launch_bounds__(BLK, 4) void kan_mfma(const float* __restrict__ X,
                                                   float* __restrict__ Y,
                                                   const float* __restrict__ grid,
                                                   const unsigned short* __restrict__ Wpk) {
    __shared__ __align__(16) unsigned short panel[ROWS * 576];   // 36864 B
    char* pb = (char*)&panel[0];

    const int tid  = threadIdx.x;
    const int lane = tid & 63;
    const int w    = tid >> 6;        // wave id = coltile
    const int r15  = lane & 15;
    const int kg   = lane >> 4;       // 0..3
    const int swA  = (r15 & 7) << 4;  // read-side XOR swizzle (R&7 == r15&7 for R=16m+r15)

    const int b  = blockIdx.x >> 7;          // image
    const int p0 = (blockIdx.x & 127) * 32;  // pixel base for this block's 32 rows

    // uniform grid: only g0 and 1/h needed
    const float g0   = sgpr(grid[0]);
    const float invh = sgpr(1.0f / (grid[4] - grid[3]));

    // Dense uniform cubic B-spline eval: pieces P0..P3 occupy slots c-3..c.
    // Dense 8-slot row built by 128-bit shift of packed bf16 quad; one b128 write.
    // Scalar casts (not inline-asm cvt_pk) per m240: compiler schedules/fuses better.
    auto writeEval = [&](int R, int i, float v, int siluBase) {
        float t = (v - g0) * invh;
        float cfl = floorf(t);
        int c = (int)cfl;
        float u = t - cfl;
        float u2 = u * u, u3 = u2 * u, omu = 1.0f - u;
        float P0f = omu * omu * omu * (1.0f / 6.0f);
        float P1f = (4.0f / 6.0f) + (0.5f * u3 - u2);
        float P2f = (1.0f / 6.0f) + 0.5f * (u + u2 - u3);
        float P3f = u3 * (1.0f / 6.0f);
        unsigned int lo32 = ((unsigned int)f2bf_fast(P1f) << 16) | f2bf_fast(P0f);
        unsigned int hi32 = ((unsigned int)f2bf_fast(P3f) << 16) | f2bf_fast(P2f);
        unsigned long long p64 = ((unsigned long long)hi32 << 32) | lo32;
        bool inr = (t >= 0.0f) && (c <= 10);
        int cc = inr ? c : 3;                  // safe shift domain; masked below
        int sh = 16 * cc - 48;                 // in [-48, 112]
        unsigned long long l  = p64 << (sh & 63);
        unsigned long long rr = p64 >> ((-sh) & 63);
        unsigned long long h  = p64 >> ((64 - sh) & 63);
        unsigned long long h2 = p64 << ((sh - 64) & 63);
        unsigned long long r0 = sh < 0 ? rr : (sh < 64 ? l : 0ull);
        unsigned long long r1 = sh >= 64 ? h2 : (sh > 0 ? h : 0ull);
        if (!inr) { r0 = 0ull; r1 = 0ull; }
        int sw = (R & 7) << 4;
        ull2 o2; o2[0] = r0; o2[1] = r1;
        *(ull2*)(pb + ((R * 1152 + 16 * i) ^ sw)) = o2;        // 16B-aligned; swizzle keeps alignment
        float s = v / (1.0f + __expf(-v));                     // silu
        *(unsigned short*)(pb + ((R * 1152 + siluBase + 2 * i) ^ sw)) = f2bf_fast(s);
    };

    const unsigned short* WH0 = Wpk;
    const unsigned short* WH1 = Wpk + WE0;
    const unsigned short* WH2 = Wpk + WE0 + WE1;
    const unsigned short* WL0 = Wpk + WE_ALL;
    const unsigned short* WL1 = Wpk + WE_ALL + WE0;
    const unsigned short* WL2 = Wpk + WE_ALL + WE0 + WE1;

    // ---- phase 0: L0 pad zero (logical bytes [216,256) per row) + panel build ----
    if (tid < 96) {
        int r = tid / 3, part = tid % 3;
        int sw = (r & 7) << 4;
        char* base = pb + r * 1152;
        if (part == 0) *(unsigned long long*)(base + (216 ^ sw)) = 0ull;
        else if (part == 1) { ull2 z; z[0] = 0; z[1] = 0; *(ull2*)(base + (224 ^ sw)) = z; }
        else                { ull2 z; z[0] = 0; z[1] = 0; *(ull2*)(base + (240 ^ sw)) = z; }
    }
    {
        int R = tid & 31, i = tid >> 5;
        writeEval(R, i, X[(b * D0 + i) * HWP + p0 + R], 192);
        if (tid < 128) {
            int R2 = (tid + 256) & 31, i2 = (tid + 256) >> 5;
            writeEval(R2, i2, X[(b * D0 + i2) * HWP + p0 + R2], 192);
        }
    }
    __syncthreads();

    // ---- layer 0 MFMA ----
    float4v acc0, acc1;
    mfma_layer<S0c, T0c>(WH0, WL0, w, lane, r15, kg, swA, pb, acc0, acc1);
    __syncthreads();

    // ---- layer-1 panel build (each lane: 2 tiles x 4 regs = 8 evals) ----
#pragma unroll
    for (int m = 0; m < 2; ++m)
#pragma unroll
        for (int reg = 0; reg < 4; ++reg) {
            int R = 16 * m + 4 * kg + reg;            // C/D row mapping (m89)
            int ccol = 16 * w + r15;                  // C/D col mapping
            writeEval(R, ccol, m == 0 ? acc0[reg] : acc1[reg], 1024);
        }
    __syncthreads();

    // ---- layer 1 MFMA ----
    mfma_layer<S1c, T1c>(WH1, WL1, w, lane, r15, kg, swA, pb, acc0, acc1);
    __syncthreads();

    // ---- layer-2 panel build ----
#pragma unroll
    for (int m = 0; m < 2; ++m)
#pragma unroll
        for (int reg = 0; reg < 4; ++reg) {
            int R = 16 * m + 4 * kg + reg;
            int ccol = 16 * w + r15;
            writeEval(R, ccol, m == 0 ? acc0[reg] : acc1[reg], 1024);
        }
    __syncthreads();

    // ---- layer 2 MFMA (2 coltiles, waves 0,1) ----
    acc0 = (float4v){0.f, 0.f, 0.f, 0.f}; acc1 = (float4v){0.f, 0.f, 0.f, 0.f};
    if (w < 2)
        mfma_layer<S2c, T2c>(WH2, WL2, w, lane, r15, kg, swA, pb, acc0, acc1);
    __syncthreads();

    // ---- store: acc -> LDS [c][R] fp32 (pad 33 kills bank conflict), coalesced write ----
    float* fp = (float*)pb;
    if (w < 2) {
#pragma unroll
        for (int m = 0; m < 2; ++m)
#pragma unroll
            for (int reg = 0; reg < 4; ++reg) {
                int R = 16 * m + 4 * kg + reg;
                int ccol = 16 * w + r15;
                if (ccol < D3) fp[ccol * 33 + R] = (m == 0 ? acc0[reg] : acc1[reg]);
            }
    }
    __syncthreads();
#pragma unroll
    for (int q = 0; q < 3; ++q) {                     // 768 floats = 24 cols x 32 rows
        int idx = tid + BLK * q;
        int ccol = idx >> 5, R = idx & 31;
        Y[(b * D3 + ccol) * HWP + p0 + R] = fp[ccol * 33 + R];
    }
}

extern "C" void kernel_launch(void* const* d_in, const int* in_sizes, int n_in,
                              void* d_out, int out_size, void* d_ws, size_t ws_size,
                              hipStream_t stream) {
    const float* X     = (const float*)d_in[0];
    const float* grid0 = (const float*)d_in[1];
    const float* coef0 = (const float*)d_in[2];
    const float* sb0   = (const float*)d_in[3];
    const float* ss0   = (const float*)d_in[4];
    const float* coef1 = (const float*)d_in[6];
    const float* sb1   = (const float*)d_in[7];
    const float* ss1   = (const float*)d_in[8];
    const float* coef2 = (const float*)d_in[10];
    const float* sb2   = (const float*)d_in[11];
    const float* ss2   = (const float*)d_in[12];
    float* Yout = (float*)d_out;

    unsigned short* W = (unsigned short*)d_ws;
    if (ws_size < WBYTES) {
        void* sym = nullptr;
        hipGetSymbolAddress(&sym, HIP_SYMBOL(g_Wfb));
        W = (unsigned short*)sym;
    }

    hipLaunchKernelGGL(pack_w, dim3((WE_ALL + 255) / 256), dim3(256), 0, stream, W,
                       coef0, sb0, ss0, coef1, sb1, ss1, coef2, sb2, ss2);
    hipLaunchKernelGGL(kan_mfma, dim3(NROWS / ROWS), dim3(BLK), 0, stream,
                       X, Yout, grid0, W);
}